// Round 1
// 1783.593 us; speedup vs baseline: 1.1577x; 1.1577x over previous
//
#include <hip/hip_runtime.h>
#include <math.h>

// Sinkhorn: m = diag(r) * M0 * diag(c).  M0 = exp(x - rowmax) lives in d_out.
// Fused iteration: ONE read of M0 computes both the row dots (u -> r update)
// and the r-weighted column partials (-> c update), halving traffic/iter.
// ws layout: r[16384] | c[16384] | vpart[P][16384]   (P chosen from ws_size)

#define EPSV 1e-6f
#define NDIM 4096
#define NB 4
#define NROWS (NB * NDIM)        // 16384
#define SINKHORN_ITERS 20

// ---- init + iteration-1 row phase -----------------------------------------
// M0 = exp(x - rowmax); u = rowsum(M0) (c==1); r1 = 1/(u+eps);
// col partials vacc += r1*M0; also sets c = 1.
template<int RPB>
__global__ __launch_bounds__(256) void init_fused(
    const float* __restrict__ x, float* __restrict__ m0,
    float* __restrict__ r, float* __restrict__ cvec,
    float* __restrict__ vpart) {
  const int b = blockIdx.x;                // batch 0..3
  const int p = blockIdx.y;                // row chunk
  const int t = threadIdx.x;               // 0..255
  const int i0 = p * RPB;
  const float4* xb = (const float4*)(x + ((size_t)b << 24));
  float4* mb = (float4*)(m0 + ((size_t)b << 24));

  if (p == 0) {                            // c = 1 for this batch
    float4* cb4 = (float4*)(cvec + (b << 12));
#pragma unroll
    for (int k = 0; k < 4; k++) cb4[k * 256 + t] = make_float4(1.f, 1.f, 1.f, 1.f);
  }

  float4 vacc[4];
#pragma unroll
  for (int k = 0; k < 4; k++) vacc[k] = make_float4(0.f, 0.f, 0.f, 0.f);

  __shared__ float smax[2][4];
  __shared__ float ssum[2][4];
  const int lane = t & 63, wid = t >> 6;

  for (int i = i0; i < i0 + RPB; i++) {
    const float4* rp = xb + ((size_t)i << 10);
    float4 a[4];
#pragma unroll
    for (int k = 0; k < 4; k++) a[k] = rp[k * 256 + t];

    float mx = -INFINITY;
#pragma unroll
    for (int k = 0; k < 4; k++)
      mx = fmaxf(mx, fmaxf(fmaxf(a[k].x, a[k].y), fmaxf(a[k].z, a[k].w)));
#pragma unroll
    for (int o = 32; o > 0; o >>= 1) mx = fmaxf(mx, __shfl_down(mx, o, 64));
    if (lane == 0) smax[i & 1][wid] = mx;
    __syncthreads();
    const float bmax = fmaxf(fmaxf(smax[i & 1][0], smax[i & 1][1]),
                             fmaxf(smax[i & 1][2], smax[i & 1][3]));

    float4 e[4];
    float dot = 0.f;
#pragma unroll
    for (int k = 0; k < 4; k++) {
      e[k].x = __expf(a[k].x - bmax);
      e[k].y = __expf(a[k].y - bmax);
      e[k].z = __expf(a[k].z - bmax);
      e[k].w = __expf(a[k].w - bmax);
      dot += e[k].x + e[k].y + e[k].z + e[k].w;
      mb[((size_t)i << 10) + k * 256 + t] = e[k];
    }
#pragma unroll
    for (int o = 32; o > 0; o >>= 1) dot += __shfl_down(dot, o, 64);
    if (lane == 0) ssum[i & 1][wid] = dot;
    __syncthreads();
    const float u = ssum[i & 1][0] + ssum[i & 1][1] + ssum[i & 1][2] + ssum[i & 1][3];
    const float rr = 1.0f / (u + EPSV);    // r_old == 1
    if (t == 0) r[(b << 12) + i] = rr;
#pragma unroll
    for (int k = 0; k < 4; k++) {
      vacc[k].x += rr * e[k].x; vacc[k].y += rr * e[k].y;
      vacc[k].z += rr * e[k].z; vacc[k].w += rr * e[k].w;
    }
  }
  float4* vp = (float4*)(vpart + (size_t)p * NROWS + (b << 12));
#pragma unroll
  for (int k = 0; k < 4; k++) vp[k * 256 + t] = vacc[k];
}

// ---- fused iteration: one M0 read -> u dot, r update, col partials --------
template<int RPB>
__global__ __launch_bounds__(256) void fused_iter(
    const float* __restrict__ m0, const float* __restrict__ cvec,
    float* __restrict__ r, float* __restrict__ vpart) {
  const int b = blockIdx.x;
  const int p = blockIdx.y;
  const int t = threadIdx.x;
  const int i0 = p * RPB;
  const float4* mb = (const float4*)(m0 + ((size_t)b << 24));
  const float4* cb = (const float4*)(cvec + (b << 12));

  __shared__ float rsh[RPB];               // r_old preload (race-free r update)
  __shared__ float sred[2][4];
  if (t < RPB) rsh[t] = r[(b << 12) + i0 + t];

  float4 cv[4];
#pragma unroll
  for (int k = 0; k < 4; k++) cv[k] = cb[k * 256 + t];
  float4 vacc[4];
#pragma unroll
  for (int k = 0; k < 4; k++) vacc[k] = make_float4(0.f, 0.f, 0.f, 0.f);

  const int lane = t & 63, wid = t >> 6;

  float4 acur[4], anxt[4];
#pragma unroll
  for (int k = 0; k < 4; k++) {
    acur[k] = mb[((size_t)i0 << 10) + k * 256 + t];
    anxt[k] = acur[k];
  }

  for (int i = i0; i < i0 + RPB; i++) {
    if (i + 1 < i0 + RPB) {                // prefetch next row (hides latency
#pragma unroll                             // under reduce + barrier)
      for (int k = 0; k < 4; k++)
        anxt[k] = mb[((size_t)(i + 1) << 10) + k * 256 + t];
    }
    float dot = 0.f;
#pragma unroll
    for (int k = 0; k < 4; k++)
      dot += acur[k].x * cv[k].x + acur[k].y * cv[k].y
           + acur[k].z * cv[k].z + acur[k].w * cv[k].w;
#pragma unroll
    for (int o = 32; o > 0; o >>= 1) dot += __shfl_down(dot, o, 64);
    if (lane == 0) sred[i & 1][wid] = dot;
    __syncthreads();                       // one barrier per row (dbuf slots)
    const float u = sred[i & 1][0] + sred[i & 1][1] + sred[i & 1][2] + sred[i & 1][3];
    const float ro = rsh[i - i0];
    const float rr = ro / (ro * u + EPSV);
    if (t == 0) r[(b << 12) + i] = rr;
#pragma unroll
    for (int k = 0; k < 4; k++) {
      vacc[k].x += rr * acur[k].x; vacc[k].y += rr * acur[k].y;
      vacc[k].z += rr * acur[k].z; vacc[k].w += rr * acur[k].w;
    }
#pragma unroll
    for (int k = 0; k < 4; k++) acur[k] = anxt[k];
  }
  float4* vp = (float4*)(vpart + (size_t)p * NROWS + (b << 12));
#pragma unroll
  for (int k = 0; k < 4; k++) vp[k * 256 + t] = vacc[k];
}

// ---- c update: v = sum of partials; c <- c/(c*v+eps) ----------------------
__global__ __launch_bounds__(256) void cupdate_kernel(
    const float* __restrict__ vpart, float* __restrict__ c, int P) {
  const int idx = blockIdx.x * 256 + threadIdx.x;  // 0..16383
  float v = 0.f;
#pragma unroll 8
  for (int p = 0; p < P; p++) v += vpart[(size_t)p * NROWS + idx];
  const float cc = c[idx];
  c[idx] = cc / (cc * v + EPSV);
}

// ---- final: out = M0 * r(i) * c(j), in place over d_out -------------------
__global__ __launch_bounds__(256) void final_kernel(
    float* __restrict__ m0, const float* __restrict__ r,
    const float* __restrict__ c) {
  const size_t idx = (size_t)blockIdx.x * 256 + threadIdx.x;  // per float4
  const size_t flat = idx * 4;
  const int row = (int)(flat >> 12);
  const int b = row >> 12;
  const int jj = (int)(flat & 4095);
  float4 m = ((float4*)m0)[idx];
  const float rv = r[row];
  const float4 cv = *(const float4*)(c + b * NDIM + jj);
  m.x *= rv * cv.x;
  m.y *= rv * cv.y;
  m.z *= rv * cv.z;
  m.w *= rv * cv.w;
  ((float4*)m0)[idx] = m;
}

extern "C" void kernel_launch(void* const* d_in, const int* in_sizes, int n_in,
                              void* d_out, int out_size, void* d_ws, size_t ws_size,
                              hipStream_t stream) {
  const float* x = (const float*)d_in[0];
  float* m0 = (float*)d_out;               // d_out doubles as M0 scratch
  float* r = (float*)d_ws;
  float* c = r + NROWS;
  float* vpart = c + NROWS;                // P * NROWS floats

  // choose chunk count P from available workspace (P=256 -> 16.8 MB vpart,
  // 1024 blocks = 4/CU; fallbacks keep correctness at smaller ws)
  const size_t fixed = (size_t)2 * NROWS * sizeof(float);
  const size_t pf = (ws_size > fixed)
      ? (ws_size - fixed) / ((size_t)NROWS * sizeof(float)) : 32;
  const int P = pf >= 256 ? 256 : pf >= 128 ? 128 : pf >= 64 ? 64 : 32;

#define RUN(PP, RPBV)                                                        \
  {                                                                          \
    dim3 g(NB, PP);                                                          \
    init_fused<RPBV><<<g, 256, 0, stream>>>(x, m0, r, c, vpart);             \
    cupdate_kernel<<<NROWS / 256, 256, 0, stream>>>(vpart, c, PP);           \
    for (int it = 1; it < SINKHORN_ITERS; it++) {                            \
      fused_iter<RPBV><<<g, 256, 0, stream>>>(m0, c, r, vpart);              \
      cupdate_kernel<<<NROWS / 256, 256, 0, stream>>>(vpart, c, PP);         \
    }                                                                        \
  }

  if (P == 256)      RUN(256, 16)
  else if (P == 128) RUN(128, 32)
  else if (P == 64)  RUN(64, 64)
  else               RUN(32, 128)
#undef RUN

  const int n_f4 = NROWS * NDIM / 4;       // 16,777,216 float4
  final_kernel<<<n_f4 / 256, 256, 0, stream>>>(m0, r, c);
}

// Round 2
// 1333.869 us; speedup vs baseline: 1.5481x; 1.3372x over previous
//
#include <hip/hip_runtime.h>
#include <math.h>

// Sinkhorn: m = diag(r) * M0 * diag(c),  M0 = exp(x - rowmax).
// M0 stored as FP16, packed into the FIRST 8KB of each row's 16KB output
// slot (pitch 16KB) -> final kernel expands fp16->fp32 in place per row
// with one __syncthreads (reads before writes, no cross-block aliasing).
// Fused iteration: one M0 read -> row dots (r update) + r-weighted column
// partials. Rows processed in PAIRS: two interleaved shuffle chains, one
// barrier per pair (double-buffered LDS slot).
// ws layout: r[16384] | c[16384] | vpart[P][16384]

#define EPSV 1e-6f
#define NDIM 4096
#define NB 4
#define NROWS (NB * NDIM)        // 16384
#define SINKHORN_ITERS 20

typedef _Float16 half4v __attribute__((ext_vector_type(4)));
typedef _Float16 half8v __attribute__((ext_vector_type(8)));

#define ROW_BYTES ((size_t)NDIM * 4)   // 16KB output slot per row

// ---- init + iteration-1 row phase -----------------------------------------
// M0h = fp16(exp(x - rowmax)); u = rowsum (c==1); r1 = 1/(u+eps);
// col partials vacc += r1*M0; c = 1.
template<int RPB>
__global__ __launch_bounds__(256) void init_fused(
    const float* __restrict__ x, void* __restrict__ m0,
    float* __restrict__ r, float* __restrict__ cvec,
    float* __restrict__ vpart) {
  const int b = blockIdx.x;                // batch 0..3
  const int p = blockIdx.y;                // row chunk
  const int t = threadIdx.x;               // 0..255
  const int i0 = p * RPB;
  const float4* xb = (const float4*)(x + ((size_t)b << 24));

  if (p == 0) {                            // c = 1 for this batch
    float4* cb4 = (float4*)(cvec + (b << 12));
#pragma unroll
    for (int k = 0; k < 4; k++) cb4[k * 256 + t] = make_float4(1.f, 1.f, 1.f, 1.f);
  }

  float4 vacc[4];
#pragma unroll
  for (int k = 0; k < 4; k++) vacc[k] = make_float4(0.f, 0.f, 0.f, 0.f);

  __shared__ float smax[4];
  __shared__ float ssum[4];
  const int lane = t & 63, wid = t >> 6;

  for (int i = i0; i < i0 + RPB; i++) {
    const int R = (b << 12) + i;
    const float4* rp = xb + ((size_t)i << 10);
    float4 a[4];
#pragma unroll
    for (int k = 0; k < 4; k++) a[k] = rp[k * 256 + t];

    float mx = -INFINITY;
#pragma unroll
    for (int k = 0; k < 4; k++)
      mx = fmaxf(mx, fmaxf(fmaxf(a[k].x, a[k].y), fmaxf(a[k].z, a[k].w)));
#pragma unroll
    for (int o = 32; o > 0; o >>= 1) mx = fmaxf(mx, __shfl_down(mx, o, 64));
    if (lane == 0) smax[wid] = mx;
    __syncthreads();
    const float bmax = fmaxf(fmaxf(smax[0], smax[1]), fmaxf(smax[2], smax[3]));

    float4 e[4];
    float dot = 0.f;
#pragma unroll
    for (int k = 0; k < 4; k++) {
      e[k].x = __expf(a[k].x - bmax);
      e[k].y = __expf(a[k].y - bmax);
      e[k].z = __expf(a[k].z - bmax);
      e[k].w = __expf(a[k].w - bmax);
      dot += e[k].x + e[k].y + e[k].z + e[k].w;
      // fp16 store: col = k*1024 + 4t -> byte k*2048 + 8t in row slot
      half4v h;
      h[0] = (_Float16)e[k].x; h[1] = (_Float16)e[k].y;
      h[2] = (_Float16)e[k].z; h[3] = (_Float16)e[k].w;
      *(half4v*)((char*)m0 + (size_t)R * ROW_BYTES + k * 2048 + 8 * t) = h;
    }
#pragma unroll
    for (int o = 32; o > 0; o >>= 1) dot += __shfl_down(dot, o, 64);
    if (lane == 0) ssum[wid] = dot;
    __syncthreads();
    const float u = ssum[0] + ssum[1] + ssum[2] + ssum[3];
    const float rr = 1.0f / (u + EPSV);    // r_old == 1
    if (t == 0) r[R] = rr;
#pragma unroll
    for (int k = 0; k < 4; k++) {
      vacc[k].x += rr * e[k].x; vacc[k].y += rr * e[k].y;
      vacc[k].z += rr * e[k].z; vacc[k].w += rr * e[k].w;
    }
  }
  float4* vp = (float4*)(vpart + (size_t)p * NROWS + (b << 12));
#pragma unroll
  for (int k = 0; k < 4; k++) vp[k * 256 + t] = vacc[k];
}

// ---- fused iteration: one fp16 M0 read -> u dots (row pair), r update,
// ---- col partials ---------------------------------------------------------
// thread t covers cols [8t,8t+8) and [2048+8t,2048+8t+8)  (chunks t, 256+t)
template<int RPB>
__global__ __launch_bounds__(256) void fused_iter(
    const void* __restrict__ m0, const float* __restrict__ cvec,
    float* __restrict__ r, float* __restrict__ vpart) {
  const int b = blockIdx.x;
  const int p = blockIdx.y;
  const int t = threadIdx.x;
  const int i0 = p * RPB;

  __shared__ float rsh[RPB];               // r_old preload (race-free)
  __shared__ float sred[2][2][4];          // [round parity][row in pair][wave]
  if (t < RPB) rsh[t] = r[(b << 12) + i0 + t];

  const float4* cb = (const float4*)(cvec + (b << 12));
  float cvf[16];
  {
    float4 c0 = cb[2 * t], c1 = cb[2 * t + 1];
    float4 c2 = cb[512 + 2 * t], c3 = cb[512 + 2 * t + 1];
    cvf[0] = c0.x; cvf[1] = c0.y; cvf[2] = c0.z; cvf[3] = c0.w;
    cvf[4] = c1.x; cvf[5] = c1.y; cvf[6] = c1.z; cvf[7] = c1.w;
    cvf[8] = c2.x; cvf[9] = c2.y; cvf[10] = c2.z; cvf[11] = c2.w;
    cvf[12] = c3.x; cvf[13] = c3.y; cvf[14] = c3.z; cvf[15] = c3.w;
  }
  float vac[16];
#pragma unroll
  for (int k = 0; k < 16; k++) vac[k] = 0.f;

  const int lane = t & 63, wid = t >> 6;
  __syncthreads();                         // rsh visible

#define M0ROW(i) ((const half8v*)((const char*)m0 + (size_t)((b << 12) + (i)) * ROW_BYTES))

  // prologue: load first pair
  half8v n00 = M0ROW(i0)[t],     n01 = M0ROW(i0)[256 + t];
  half8v n10 = M0ROW(i0 + 1)[t], n11 = M0ROW(i0 + 1)[256 + t];

  int rnd = 0;
  for (int i = i0; i < i0 + RPB; i += 2, rnd ^= 1) {
    float a0[16], a1[16];
#pragma unroll
    for (int k = 0; k < 8; k++) {
      a0[k] = (float)n00[k]; a0[8 + k] = (float)n01[k];
      a1[k] = (float)n10[k]; a1[8 + k] = (float)n11[k];
    }
    if (i + 2 < i0 + RPB) {                // prefetch next pair
      n00 = M0ROW(i + 2)[t]; n01 = M0ROW(i + 2)[256 + t];
      n10 = M0ROW(i + 3)[t]; n11 = M0ROW(i + 3)[256 + t];
    }
    float d0 = 0.f, d1 = 0.f;
#pragma unroll
    for (int k = 0; k < 16; k++) { d0 += a0[k] * cvf[k]; d1 += a1[k] * cvf[k]; }
#pragma unroll
    for (int o = 32; o > 0; o >>= 1) {     // two interleaved chains (ILP)
      d0 += __shfl_down(d0, o, 64);
      d1 += __shfl_down(d1, o, 64);
    }
    if (lane == 0) { sred[rnd][0][wid] = d0; sred[rnd][1][wid] = d1; }
    __syncthreads();                       // one barrier per row PAIR
    const float u0 = sred[rnd][0][0] + sred[rnd][0][1] + sred[rnd][0][2] + sred[rnd][0][3];
    const float u1 = sred[rnd][1][0] + sred[rnd][1][1] + sred[rnd][1][2] + sred[rnd][1][3];
    const float ro0 = rsh[i - i0], ro1 = rsh[i - i0 + 1];
    const float rr0 = ro0 / (ro0 * u0 + EPSV);
    const float rr1 = ro1 / (ro1 * u1 + EPSV);
    if (t == 0) { r[(b << 12) + i] = rr0; r[(b << 12) + i + 1] = rr1; }
#pragma unroll
    for (int k = 0; k < 16; k++) vac[k] += rr0 * a0[k] + rr1 * a1[k];
  }
#undef M0ROW

  float4* vp = (float4*)(vpart + (size_t)p * NROWS + (b << 12));
  vp[2 * t]       = make_float4(vac[0], vac[1], vac[2], vac[3]);
  vp[2 * t + 1]   = make_float4(vac[4], vac[5], vac[6], vac[7]);
  vp[512 + 2 * t]     = make_float4(vac[8], vac[9], vac[10], vac[11]);
  vp[512 + 2 * t + 1] = make_float4(vac[12], vac[13], vac[14], vac[15]);
}

// ---- c update: v = sum of partials; c <- c/(c*v+eps) ----------------------
__global__ __launch_bounds__(256) void cupdate_kernel(
    const float* __restrict__ vpart, float* __restrict__ c, int P) {
  const int idx = blockIdx.x * 256 + threadIdx.x;  // 0..16383
  float v = 0.f;
#pragma unroll 8
  for (int p = 0; p < P; p++) v += vpart[(size_t)p * NROWS + idx];
  const float cc = c[idx];
  c[idx] = cc / (cc * v + EPSV);
}

// ---- final: expand fp16 row in place -> out = M0 * r(i) * c(j) ------------
// one block per row; all fp16 reads complete before any fp32 write (barrier)
__global__ __launch_bounds__(256) void final_kernel(
    void* __restrict__ m0, const float* __restrict__ r,
    const float* __restrict__ c) {
  const int R = blockIdx.x;                // 0..16383
  const int b = R >> 12;
  const int t = threadIdx.x;
  const half8v* mr = (const half8v*)((const char*)m0 + (size_t)R * ROW_BYTES);
  const half8v h0 = mr[t];                 // cols 8t..8t+7
  const half8v h1 = mr[256 + t];           // cols 2048+8t..
  __syncthreads();                         // reads drained before writes
  const float rv = r[R];
  const float4* cb = (const float4*)(c + (b << 12));
  const float4 c0 = cb[2 * t], c1 = cb[2 * t + 1];
  const float4 c2 = cb[512 + 2 * t], c3 = cb[512 + 2 * t + 1];
  float4* orow = (float4*)((char*)m0 + (size_t)R * ROW_BYTES);
  float4 o;
  o.x = rv * c0.x * (float)h0[0]; o.y = rv * c0.y * (float)h0[1];
  o.z = rv * c0.z * (float)h0[2]; o.w = rv * c0.w * (float)h0[3];
  orow[2 * t] = o;
  o.x = rv * c1.x * (float)h0[4]; o.y = rv * c1.y * (float)h0[5];
  o.z = rv * c1.z * (float)h0[6]; o.w = rv * c1.w * (float)h0[7];
  orow[2 * t + 1] = o;
  o.x = rv * c2.x * (float)h1[0]; o.y = rv * c2.y * (float)h1[1];
  o.z = rv * c2.z * (float)h1[2]; o.w = rv * c2.w * (float)h1[3];
  orow[512 + 2 * t] = o;
  o.x = rv * c3.x * (float)h1[4]; o.y = rv * c3.y * (float)h1[5];
  o.z = rv * c3.z * (float)h1[6]; o.w = rv * c3.w * (float)h1[7];
  orow[512 + 2 * t + 1] = o;
}

extern "C" void kernel_launch(void* const* d_in, const int* in_sizes, int n_in,
                              void* d_out, int out_size, void* d_ws, size_t ws_size,
                              hipStream_t stream) {
  const float* x = (const float*)d_in[0];
  void* m0 = d_out;                        // d_out holds fp16 M0 (packed rows)
  float* r = (float*)d_ws;
  float* c = r + NROWS;
  float* vpart = c + NROWS;                // P * NROWS floats

  const size_t fixed = (size_t)2 * NROWS * sizeof(float);
  const size_t pf = (ws_size > fixed)
      ? (ws_size - fixed) / ((size_t)NROWS * sizeof(float)) : 32;
  const int P = pf >= 256 ? 256 : pf >= 128 ? 128 : pf >= 64 ? 64 : 32;

#define RUN(PP, RPBV)                                                        \
  {                                                                          \
    dim3 g(NB, PP);                                                          \
    init_fused<RPBV><<<g, 256, 0, stream>>>(x, m0, r, c, vpart);             \
    cupdate_kernel<<<NROWS / 256, 256, 0, stream>>>(vpart, c, PP);           \
    for (int it = 1; it < SINKHORN_ITERS; it++) {                            \
      fused_iter<RPBV><<<g, 256, 0, stream>>>(m0, c, r, vpart);              \
      cupdate_kernel<<<NROWS / 256, 256, 0, stream>>>(vpart, c, PP);         \
    }                                                                        \
  }

  if (P == 256)      RUN(256, 16)
  else if (P == 128) RUN(128, 32)
  else if (P == 64)  RUN(64, 64)
  else               RUN(32, 128)
#undef RUN

  final_kernel<<<NROWS, 256, 0, stream>>>(m0, r, c);
}